// Round 9
// baseline (186.798 us; speedup 1.0000x reference)
//
#include <hip/hip_runtime.h>

#define N_NODES 50000
#define N_EDGES 800000

// ws layout (in floats):
//  [0, 4096)           consts[k][32] (see precompute)
//  [4096, 4104)        scalars: {c, ce, wde0, wde1, wde2, pad...}
//  [4352, 4608)        gcnt[256] (ints): per-segment record counts (250 used)
//  [8192, 208192)      es[node][4]  (also fallback target)
//  [208192, 408192)    er[node][4]
//  [408192, ...)       rec[250][CAP] uint2 records {bf16 e0|e1, bf16 e2|local}
#define CONSTS_OFF 0
#define SCAL_OFF   4096
#define GCNT_OFF   4352
#define ESRS_OFF   8192
#define ESRR_OFF   208192
#define REC_OFF    408192
#define NBIN1      125              // bins per side
#define BINSZ      400              // nodes per bin (125*400 == N_NODES)
#define NSEG       250              // 2 sides * NBIN1
#define CAP        8000             // records per segment (expected 6400, sigma~80)
#define WS_NEEDED  (REC_OFF + NSEG * CAP * 2)

__global__ void precompute_kernel(
    const float* __restrict__ g,      // globals_ [8]
    const float* __restrict__ W_en,   // [16][128]
    const float* __restrict__ b_en,   // [128]
    const float* __restrict__ W_ee,   // [3][128]
    const float* __restrict__ b_ee,   // [128]
    const float* __restrict__ W1,     // [392][128]
    const float* __restrict__ b1,     // [128]
    const float* __restrict__ W2,     // [128][128]
    const float* __restrict__ b2,     // [128]
    const float* __restrict__ W_dn,   // [128]
    const float* __restrict__ b_dn,   // [1]
    const float* __restrict__ W_de,   // [128]
    const float* __restrict__ b_de,   // [1]
    float* __restrict__ ws)
{
    const int s = blockIdx.x;
    const int k = threadIdx.x;
    float* consts = ws + CONSTS_OFF;
    float* scal   = ws + SCAL_OFF;

    if (s < 16) {
        float acc = 0.f;
        for (int l = 0; l < 128; ++l)
            acc += W_en[s * 128 + l] * W1[l * 128 + k];
        consts[k * 32 + s] = acc;
    } else if (s < 19) {
        const int j = s - 16;
        float acc = 0.f;
        for (int l = 0; l < 128; ++l)
            acc += W_ee[j * 128 + l] * W1[(128 + l) * 128 + k];
        consts[k * 32 + s] = acc;
    } else if (s < 22) {
        const int j = s - 19;
        float acc = 0.f;
        for (int l = 0; l < 128; ++l)
            acc += W_ee[j * 128 + l] * W1[(256 + l) * 128 + k];
        consts[k * 32 + s] = acc;
    } else if (s == 22) {
        float acc = b1[k];
        for (int l = 0; l < 128; ++l)
            acc += b_en[l] * W1[l * 128 + k];
        for (int j = 0; j < 8; ++j)
            acc += g[j] * W1[(384 + j) * 128 + k];
        consts[k * 32 + 22] = acc;
    } else if (s == 23) {
        float acc = 0.f;
        for (int l = 0; l < 128; ++l)
            acc += b_ee[l] * W1[(128 + l) * 128 + k];
        consts[k * 32 + 23] = acc;
    } else if (s == 24) {
        float acc = 0.f;
        for (int l = 0; l < 128; ++l)
            acc += b_ee[l] * W1[(256 + l) * 128 + k];
        consts[k * 32 + 24] = acc;
    } else if (s == 25) {
        float acc = 0.f;
        for (int j = 0; j < 128; ++j)
            acc += W2[k * 128 + j] * W_dn[j];
        consts[k * 32 + 25] = acc;
        consts[k * 32 + 26] = 0.f;
        consts[k * 32 + 27] = 0.f;
    } else {
        // s == 26: scalars + zero the segment counters (replaces a memset launch)
        int* gcnt = (int*)(ws + GCNT_OFF);
        gcnt[k] = 0;
        gcnt[128 + k] = 0;
        if (k == 0) {
            float c = b_dn[0];
            for (int j = 0; j < 128; ++j) c += b2[j] * W_dn[j];
            scal[0] = c;
            float ce = b_de[0];
            for (int l = 0; l < 128; ++l) ce += b_ee[l] * W_de[l];
            scal[1] = ce;
            scal[5] = 0.f; scal[6] = 0.f; scal[7] = 0.f;
        }
        if (k < 3) {
            float acc = 0.f;
            for (int l = 0; l < 128; ++l)
                acc += W_ee[k * 128 + l] * W_de[l];
            scal[2 + k] = acc;
        }
    }
}

__device__ __forceinline__ unsigned bf16_bits(float x) {
    // round-to-nearest-even bf16, returned in the HIGH 16 bits position >> 16
    unsigned u = __float_as_uint(x);
    return (u + 0x7FFFu + ((u >> 16) & 1u)) >> 16;
}

__device__ __forceinline__ void emit_rec(
    uint2* __restrict__ rec, const int* __restrict__ lbase, int* __restrict__ cur,
    int seg, int local, float x, float y, float z)
{
    int slot = lbase[seg] + atomicAdd(&cur[seg], 1);
    if (slot >= CAP) slot = CAP - 1;  // statistical impossibility; safety clamp
    uint2 r;
    r.x = (bf16_bits(x) << 16) | bf16_bits(y);
    r.y = (bf16_bits(z) << 16) | (unsigned)local;
    rec[(size_t)seg * CAP + slot] = r;
}

// Phase A: single pass over edges. LDS histogram over 250 segments ->
// global base -> scatter 8B records into per-segment slices. Fuses edges_out.
__global__ __launch_bounds__(256) void bucket_kernel(
    const float* __restrict__ edges,     // [E][3]
    const int*   __restrict__ senders,   // [E]
    const int*   __restrict__ receivers, // [E]
    const float* __restrict__ ws_ro,     // scalars
    int*   __restrict__ gcnt,            // [NSEG]
    uint2* __restrict__ rec,             // [NSEG][CAP]
    float* __restrict__ out_edges)       // d_out + N_NODES
{
    __shared__ int hist[NSEG], lbase[NSEG], cur[NSEG];
    const int tid = threadIdx.x;
    for (int i = tid; i < NSEG; i += 256) { hist[i] = 0; cur[i] = 0; }
    __syncthreads();

    const int e4 = (blockIdx.x * 256 + tid) * 4;
    const bool act = e4 < N_EDGES;   // N_EDGES % 4 == 0, quads never straddle

    int4 s4 = make_int4(0, 0, 0, 0), r4 = s4;
    unsigned bs0 = 0, bs1 = 0, bs2 = 0, bs3 = 0, br0 = 0, br1 = 0, br2 = 0, br3 = 0;
    if (act) {
        s4 = *(const int4*)(senders + e4);
        r4 = *(const int4*)(receivers + e4);
        bs0 = (unsigned)s4.x / BINSZ; bs1 = (unsigned)s4.y / BINSZ;
        bs2 = (unsigned)s4.z / BINSZ; bs3 = (unsigned)s4.w / BINSZ;
        br0 = (unsigned)r4.x / BINSZ; br1 = (unsigned)r4.y / BINSZ;
        br2 = (unsigned)r4.z / BINSZ; br3 = (unsigned)r4.w / BINSZ;
        atomicAdd(&hist[bs0], 1); atomicAdd(&hist[bs1], 1);
        atomicAdd(&hist[bs2], 1); atomicAdd(&hist[bs3], 1);
        atomicAdd(&hist[NBIN1 + br0], 1); atomicAdd(&hist[NBIN1 + br1], 1);
        atomicAdd(&hist[NBIN1 + br2], 1); atomicAdd(&hist[NBIN1 + br3], 1);
    }
    __syncthreads();
    for (int i = tid; i < NSEG; i += 256)
        lbase[i] = atomicAdd(&gcnt[i], hist[i]);
    __syncthreads();

    if (act) {
        const float4* ep = (const float4*)(edges + (size_t)e4 * 3);
        const float4 f0 = ep[0], f1 = ep[1], f2 = ep[2];
        // fused edge decoder (fp32 exact)
        const float* scal = ws_ro + SCAL_OFF;
        const float w0 = scal[2], w1 = scal[3], w2 = scal[4], cb = scal[1];
        float4 o;
        o.x = fmaf(f0.x, w0, fmaf(f0.y, w1, fmaf(f0.z, w2, cb)));
        o.y = fmaf(f0.w, w0, fmaf(f1.x, w1, fmaf(f1.y, w2, cb)));
        o.z = fmaf(f1.z, w0, fmaf(f1.w, w1, fmaf(f2.x, w2, cb)));
        o.w = fmaf(f2.y, w0, fmaf(f2.z, w1, fmaf(f2.w, w2, cb)));
        *(float4*)(out_edges + e4) = o;
        // e0: f0.x f0.y f0.z | e1: f0.w f1.x f1.y | e2: f1.z f1.w f2.x | e3: f2.y f2.z f2.w
        emit_rec(rec, lbase, cur, bs0,         s4.x - bs0 * BINSZ, f0.x, f0.y, f0.z);
        emit_rec(rec, lbase, cur, bs1,         s4.y - bs1 * BINSZ, f0.w, f1.x, f1.y);
        emit_rec(rec, lbase, cur, bs2,         s4.z - bs2 * BINSZ, f1.z, f1.w, f2.x);
        emit_rec(rec, lbase, cur, bs3,         s4.w - bs3 * BINSZ, f2.y, f2.z, f2.w);
        emit_rec(rec, lbase, cur, NBIN1 + br0, r4.x - br0 * BINSZ, f0.x, f0.y, f0.z);
        emit_rec(rec, lbase, cur, NBIN1 + br1, r4.y - br1 * BINSZ, f0.w, f1.x, f1.y);
        emit_rec(rec, lbase, cur, NBIN1 + br2, r4.z - br2 * BINSZ, f1.z, f1.w, f2.x);
        emit_rec(rec, lbase, cur, NBIN1 + br3, r4.w - br3 * BINSZ, f2.y, f2.z, f2.w);
    }
}

// Phase B: one block per segment streams its dense 8B-record slice, SoA LDS
// accumulate (bank = li%32), writes final es/er slice with plain stores.
__global__ __launch_bounds__(1024) void accum_kernel(
    const int* __restrict__ gcnt,
    const uint2* __restrict__ rec,    // [NSEG][CAP]
    float* __restrict__ es,           // [N_NODES][4]
    float* __restrict__ er)           // [N_NODES][4]
{
    __shared__ float accx[BINSZ], accy[BINSZ], accz[BINSZ], accw[BINSZ];
    const int tid = threadIdx.x;
    if (tid < BINSZ) {
        accx[tid] = 0.f; accy[tid] = 0.f; accz[tid] = 0.f; accw[tid] = 0.f;
    }
    __syncthreads();

    const int seg = blockIdx.x;
    int cnt = gcnt[seg];
    if (cnt > CAP) cnt = CAP;
    const uint2* r = rec + (size_t)seg * CAP;

    for (int i = tid; i < cnt; i += 1024) {
        const uint2 rc = r[i];
        const float x = __uint_as_float(rc.x & 0xFFFF0000u);
        const float y = __uint_as_float(rc.x << 16);
        const float z = __uint_as_float(rc.y & 0xFFFF0000u);
        const int  li = (int)(rc.y & 0xFFFFu);
        atomicAdd(&accx[li], x);
        atomicAdd(&accy[li], y);
        atomicAdd(&accz[li], z);
        atomicAdd(&accw[li], 1.0f);
    }
    __syncthreads();

    float* base = (seg < NBIN1)
                ? es + (size_t)seg * BINSZ * 4
                : er + (size_t)(seg - NBIN1) * BINSZ * 4;
    if (tid < BINSZ) {
        float4* dst = (float4*)base;
        dst[tid] = make_float4(accx[tid], accy[tid], accz[tid], accw[tid]);
    }
}

// ---- fallback path (tiny ws): global-atomic scatter + edge decode ----
__global__ __launch_bounds__(256) void edge_kernel_atomic(
    const float* __restrict__ edges,
    const int*   __restrict__ senders,
    const int*   __restrict__ receivers,
    float* __restrict__ es,
    float* __restrict__ er,
    const float* __restrict__ ws_ro,
    float* __restrict__ out_edges)
{
    const int e = blockIdx.x * 256 + threadIdx.x;
    if (e >= N_EDGES) return;
    const float e0 = edges[e * 3 + 0];
    const float e1 = edges[e * 3 + 1];
    const float e2 = edges[e * 3 + 2];
    const int s = senders[e];
    const int r = receivers[e];
    atomicAdd(&es[s * 4 + 0], e0);
    atomicAdd(&es[s * 4 + 1], e1);
    atomicAdd(&es[s * 4 + 2], e2);
    atomicAdd(&es[s * 4 + 3], 1.0f);
    atomicAdd(&er[r * 4 + 0], e0);
    atomicAdd(&er[r * 4 + 1], e1);
    atomicAdd(&er[r * 4 + 2], e2);
    atomicAdd(&er[r * 4 + 3], 1.0f);
    const float* scal = ws_ro + SCAL_OFF;
    out_edges[e] = e0 * scal[2] + e1 * scal[3] + e2 * scal[4] + scal[1];
}

// Node MLP. Consts read with wave-uniform addresses from global memory ->
// s_load path on the SMEM pipe (no LDS broadcast cost). 64-thread blocks.
__global__ __launch_bounds__(64) void node_kernel(
    const float* __restrict__ nodes,  // [N][16]
    const float* __restrict__ ws,
    float* __restrict__ out_nodes)    // d_out
{
    const int n = blockIdx.x * 64 + threadIdx.x;
    if (n >= N_NODES) return;

    const float4* np4 = (const float4*)(nodes + (size_t)n * 16);
    const float4 n0 = np4[0], n1 = np4[1], n2 = np4[2], n3 = np4[3];
    const float4 es = *(const float4*)(ws + ESRS_OFF + (size_t)n * 4);
    const float4 er = *(const float4*)(ws + ESRR_OFF + (size_t)n * 4);

    const float* cst = ws + CONSTS_OFF;  // wave-uniform reads below
    float acc = 0.f;
#pragma unroll 4
    for (int k = 0; k < 128; ++k) {
        const float4 m0 = *(const float4*)(cst + k * 32 + 0);
        const float4 m1 = *(const float4*)(cst + k * 32 + 4);
        const float4 m2 = *(const float4*)(cst + k * 32 + 8);
        const float4 m3 = *(const float4*)(cst + k * 32 + 12);
        const float4 q0 = *(const float4*)(cst + k * 32 + 16);
        const float4 q1 = *(const float4*)(cst + k * 32 + 20);
        const float4 q2 = *(const float4*)(cst + k * 32 + 24);
        float pre = q1.z
            + n0.x * m0.x + n0.y * m0.y + n0.z * m0.z + n0.w * m0.w
            + n1.x * m1.x + n1.y * m1.y + n1.z * m1.z + n1.w * m1.w
            + n2.x * m2.x + n2.y * m2.y + n2.z * m2.z + n2.w * m2.w
            + n3.x * m3.x + n3.y * m3.y + n3.z * m3.z + n3.w * m3.w
            + es.x * q0.x + es.y * q0.y + es.z * q0.z
            + er.x * q0.w + er.y * q1.x + er.z * q1.y
            + es.w * q1.w + er.w * q2.x;
        acc += fmaxf(pre, 0.f) * q2.y;
    }
    const float* scal = ws + SCAL_OFF;
    out_nodes[n] = acc + scal[0];
}

extern "C" void kernel_launch(void* const* d_in, const int* in_sizes, int n_in,
                              void* d_out, int out_size, void* d_ws, size_t ws_size,
                              hipStream_t stream) {
    const float* nodes     = (const float*)d_in[0];
    const float* edges     = (const float*)d_in[1];
    const float* globals_  = (const float*)d_in[2];
    const int*   senders   = (const int*)d_in[3];
    const int*   receivers = (const int*)d_in[4];
    const float* W_en = (const float*)d_in[5];
    const float* b_en = (const float*)d_in[6];
    const float* W_ee = (const float*)d_in[7];
    const float* b_ee = (const float*)d_in[8];
    const float* W1   = (const float*)d_in[9];
    const float* b1   = (const float*)d_in[10];
    const float* W2   = (const float*)d_in[11];
    const float* b2   = (const float*)d_in[12];
    const float* W_dn = (const float*)d_in[13];
    const float* b_dn = (const float*)d_in[14];
    const float* W_de = (const float*)d_in[15];
    const float* b_de = (const float*)d_in[16];

    float* ws = (float*)d_ws;
    float* out = (float*)d_out;

    precompute_kernel<<<27, 128, 0, stream>>>(
        globals_, W_en, b_en, W_ee, b_ee, W1, b1, W2, b2,
        W_dn, b_dn, W_de, b_de, ws);

    const long ws_floats = (long)(ws_size / 4);
    const bool big = ws_floats >= (long)WS_NEEDED;

    int*   gcnt = (int*)(ws + GCNT_OFF);
    uint2* rec  = (uint2*)(ws + REC_OFF);
    float* es   = ws + ESRS_OFF;
    float* er   = ws + ESRR_OFF;

    if (big) {
        bucket_kernel<<<(N_EDGES / 4 + 255) / 256, 256, 0, stream>>>(
            edges, senders, receivers, ws, gcnt, rec, out + N_NODES);
        accum_kernel<<<NSEG, 1024, 0, stream>>>(gcnt, rec, es, er);
    } else {
        hipMemsetAsync(es, 0, (size_t)N_NODES * 8 * sizeof(float), stream);
        edge_kernel_atomic<<<(N_EDGES + 255) / 256, 256, 0, stream>>>(
            edges, senders, receivers, es, er, ws, out + N_NODES);
    }

    node_kernel<<<(N_NODES + 63) / 64, 64, 0, stream>>>(nodes, ws, out);
}

// Round 10
// 176.605 us; speedup vs baseline: 1.0577x; 1.0577x over previous
//
#include <hip/hip_runtime.h>

#define N_NODES 50000
#define N_EDGES 800000

// ws layout (in floats):
//  [0, 400000)        esr[node][8] (fallback path only)
//  [400000, 404096)   consts[k][32] (see precompute)
//  [404096, 404104)   scalars: {c, ce, wde0, wde1, wde2, pad...}
//  [404608, ...)      part_s[c][node][4] then part_r[c][node][4]
#define ESR_OFF    0
#define CONSTS_OFF 400000
#define SCAL_OFF   404096
#define PART_OFF   404608

#define NBINS      25
#define BINSZ      2000   // nodes per bin-side; LDS = 2000*4*4 = 32000 B; 4 blocks/CU
#define MAX_CHUNKS 20

__global__ void precompute_kernel(
    const float* __restrict__ g,      // globals_ [8]
    const float* __restrict__ W_en,   // [16][128]
    const float* __restrict__ b_en,   // [128]
    const float* __restrict__ W_ee,   // [3][128]
    const float* __restrict__ b_ee,   // [128]
    const float* __restrict__ W1,     // [392][128]
    const float* __restrict__ b1,     // [128]
    const float* __restrict__ W2,     // [128][128]
    const float* __restrict__ b2,     // [128]
    const float* __restrict__ W_dn,   // [128]
    const float* __restrict__ b_dn,   // [1]
    const float* __restrict__ W_de,   // [128]
    const float* __restrict__ b_de,   // [1]
    float* __restrict__ ws)
{
    const int s = blockIdx.x;
    const int k = threadIdx.x;
    float* consts = ws + CONSTS_OFF;
    float* scal   = ws + SCAL_OFF;

    if (s < 16) {
        float acc = 0.f;
        for (int l = 0; l < 128; ++l)
            acc += W_en[s * 128 + l] * W1[l * 128 + k];
        consts[k * 32 + s] = acc;
    } else if (s < 19) {
        const int j = s - 16;
        float acc = 0.f;
        for (int l = 0; l < 128; ++l)
            acc += W_ee[j * 128 + l] * W1[(128 + l) * 128 + k];
        consts[k * 32 + s] = acc;
    } else if (s < 22) {
        const int j = s - 19;
        float acc = 0.f;
        for (int l = 0; l < 128; ++l)
            acc += W_ee[j * 128 + l] * W1[(256 + l) * 128 + k];
        consts[k * 32 + s] = acc;
    } else if (s == 22) {
        float acc = b1[k];
        for (int l = 0; l < 128; ++l)
            acc += b_en[l] * W1[l * 128 + k];
        for (int j = 0; j < 8; ++j)
            acc += g[j] * W1[(384 + j) * 128 + k];
        consts[k * 32 + 22] = acc;
    } else if (s == 23) {
        float acc = 0.f;
        for (int l = 0; l < 128; ++l)
            acc += b_ee[l] * W1[(128 + l) * 128 + k];
        consts[k * 32 + 23] = acc;
    } else if (s == 24) {
        float acc = 0.f;
        for (int l = 0; l < 128; ++l)
            acc += b_ee[l] * W1[(256 + l) * 128 + k];
        consts[k * 32 + 24] = acc;
    } else if (s == 25) {
        float acc = 0.f;
        for (int j = 0; j < 128; ++j)
            acc += W2[k * 128 + j] * W_dn[j];
        consts[k * 32 + 25] = acc;
        consts[k * 32 + 26] = 0.f;
        consts[k * 32 + 27] = 0.f;
    } else {
        if (k == 0) {
            float c = b_dn[0];
            for (int j = 0; j < 128; ++j) c += b2[j] * W_dn[j];
            scal[0] = c;
            float ce = b_de[0];
            for (int l = 0; l < 128; ++l) ce += b_ee[l] * W_de[l];
            scal[1] = ce;
            scal[5] = 0.f; scal[6] = 0.f; scal[7] = 0.f;
        }
        if (k < 3) {
            float acc = 0.f;
            for (int l = 0; l < 128; ++l)
                acc += W_ee[k * 128 + l] * W_de[l];
            scal[2 + k] = acc;
        }
    }
}

// Pure streaming edge decoder.
__global__ __launch_bounds__(256) void edge_out_kernel(
    const float* __restrict__ edges,
    const float* __restrict__ ws,
    float* __restrict__ out_edges)
{
    const int e4 = (blockIdx.x * 256 + threadIdx.x) * 4;
    if (e4 >= N_EDGES) return;
    const float* scal = ws + SCAL_OFF;
    const float w0 = scal[2], w1 = scal[3], w2 = scal[4], cb = scal[1];
    const float4* ep = (const float4*)(edges + (size_t)e4 * 3);
    const float4 f0 = ep[0], f1 = ep[1], f2 = ep[2];
    float4 o;
    o.x = fmaf(f0.x, w0, fmaf(f0.y, w1, fmaf(f0.z, w2, cb)));
    o.y = fmaf(f0.w, w0, fmaf(f1.x, w1, fmaf(f1.y, w2, cb)));
    o.z = fmaf(f1.z, w0, fmaf(f1.w, w1, fmaf(f2.x, w2, cb)));
    o.w = fmaf(f2.y, w0, fmaf(f2.z, w1, fmaf(f2.w, w2, cb)));
    *(float4*)(out_edges + e4) = o;
}

// Split-side binned aggregation, 32KB LDS -> 4 blocks/CU (32 waves/CU),
// 8 edges/thread with 1-deep index prefetch pipeline.  [R5 best: 174.5 µs]
__global__ __launch_bounds__(512, 8) void agg_kernel(
    const float* __restrict__ edges,     // [E][3]
    const int*   __restrict__ senders,   // [E]
    const int*   __restrict__ receivers, // [E]
    float* __restrict__ part_s,          // [nchunks][N_NODES][4]
    float* __restrict__ part_r,          // [nchunks][N_NODES][4]
    int ce)                              // edges per chunk (multiple of 8)
{
    __shared__ float4 acc4[BINSZ];       // [BINSZ][4] floats = 32000 B
    float* acc = (float*)acc4;
    const int tid = threadIdx.x;
    for (int i = tid; i < BINSZ; i += 512)
        acc4[i] = make_float4(0.f, 0.f, 0.f, 0.f);
    __syncthreads();

    const int chunk  = blockIdx.x;
    const int binid  = blockIdx.y;
    const bool is_s  = binid < NBINS;
    const int bin    = is_s ? binid : binid - NBINS;
    const int lo     = bin * BINSZ;
    const int* __restrict__ idx = is_s ? senders : receivers;

    const int e_beg = chunk * ce;
    const int e_end = min(e_beg + ce, N_EDGES);
    const int STRIDE = 512 * 8;

    int e8 = e_beg + tid * 8;
    int4 ia = make_int4(-1, -1, -1, -1), ib = ia;
    if (e8 < e_end) {
        ia = *(const int4*)(idx + e8);
        ib = *(const int4*)(idx + e8 + 4);
    }
    while (e8 < e_end) {
        const int e8n = e8 + STRIDE;
        int4 ian = ia, ibn = ib;
        if (e8n < e_end) {                    // prefetch next iteration's indices
            ian = *(const int4*)(idx + e8n);
            ibn = *(const int4*)(idx + e8n + 4);
        }
        const unsigned d0 = (unsigned)(ia.x - lo), d1 = (unsigned)(ia.y - lo);
        const unsigned d2 = (unsigned)(ia.z - lo), d3 = (unsigned)(ia.w - lo);
        const unsigned d4 = (unsigned)(ib.x - lo), d5 = (unsigned)(ib.y - lo);
        const unsigned d6 = (unsigned)(ib.z - lo), d7 = (unsigned)(ib.w - lo);
        if ((d0 < BINSZ) | (d1 < BINSZ) | (d2 < BINSZ) | (d3 < BINSZ)) {
            const float4* ep = (const float4*)(edges + (size_t)e8 * 3);
            const float4 f0 = ep[0], f1 = ep[1], f2 = ep[2];
            // e0: f0.x f0.y f0.z | e1: f0.w f1.x f1.y | e2: f1.z f1.w f2.x | e3: f2.y f2.z f2.w
            if (d0 < BINSZ) {
                atomicAdd(&acc[d0 * 4 + 0], f0.x); atomicAdd(&acc[d0 * 4 + 1], f0.y);
                atomicAdd(&acc[d0 * 4 + 2], f0.z); atomicAdd(&acc[d0 * 4 + 3], 1.0f);
            }
            if (d1 < BINSZ) {
                atomicAdd(&acc[d1 * 4 + 0], f0.w); atomicAdd(&acc[d1 * 4 + 1], f1.x);
                atomicAdd(&acc[d1 * 4 + 2], f1.y); atomicAdd(&acc[d1 * 4 + 3], 1.0f);
            }
            if (d2 < BINSZ) {
                atomicAdd(&acc[d2 * 4 + 0], f1.z); atomicAdd(&acc[d2 * 4 + 1], f1.w);
                atomicAdd(&acc[d2 * 4 + 2], f2.x); atomicAdd(&acc[d2 * 4 + 3], 1.0f);
            }
            if (d3 < BINSZ) {
                atomicAdd(&acc[d3 * 4 + 0], f2.y); atomicAdd(&acc[d3 * 4 + 1], f2.z);
                atomicAdd(&acc[d3 * 4 + 2], f2.w); atomicAdd(&acc[d3 * 4 + 3], 1.0f);
            }
        }
        if ((d4 < BINSZ) | (d5 < BINSZ) | (d6 < BINSZ) | (d7 < BINSZ)) {
            const float4* ep = (const float4*)(edges + (size_t)e8 * 3 + 12);
            const float4 f0 = ep[0], f1 = ep[1], f2 = ep[2];
            if (d4 < BINSZ) {
                atomicAdd(&acc[d4 * 4 + 0], f0.x); atomicAdd(&acc[d4 * 4 + 1], f0.y);
                atomicAdd(&acc[d4 * 4 + 2], f0.z); atomicAdd(&acc[d4 * 4 + 3], 1.0f);
            }
            if (d5 < BINSZ) {
                atomicAdd(&acc[d5 * 4 + 0], f0.w); atomicAdd(&acc[d5 * 4 + 1], f1.x);
                atomicAdd(&acc[d5 * 4 + 2], f1.y); atomicAdd(&acc[d5 * 4 + 3], 1.0f);
            }
            if (d6 < BINSZ) {
                atomicAdd(&acc[d6 * 4 + 0], f1.z); atomicAdd(&acc[d6 * 4 + 1], f1.w);
                atomicAdd(&acc[d6 * 4 + 2], f2.x); atomicAdd(&acc[d6 * 4 + 3], 1.0f);
            }
            if (d7 < BINSZ) {
                atomicAdd(&acc[d7 * 4 + 0], f2.y); atomicAdd(&acc[d7 * 4 + 1], f2.z);
                atomicAdd(&acc[d7 * 4 + 2], f2.w); atomicAdd(&acc[d7 * 4 + 3], 1.0f);
            }
        }
        ia = ian; ib = ibn;
        e8 = e8n;
    }
    __syncthreads();

    float* base = (is_s ? part_s : part_r) + (size_t)chunk * (N_NODES * 4) + (size_t)lo * 4;
    float4* dst = (float4*)base;
    for (int i = tid; i < BINSZ; i += 512)
        dst[i] = acc4[i];
}

// ---- fallback path (tiny ws): global-atomic scatter into esr[node][8] ----
__global__ __launch_bounds__(256) void edge_kernel_atomic(
    const float* __restrict__ edges,
    const int*   __restrict__ senders,
    const int*   __restrict__ receivers,
    float* __restrict__ ws)
{
    const int e = blockIdx.x * 256 + threadIdx.x;
    if (e >= N_EDGES) return;
    const float e0 = edges[e * 3 + 0];
    const float e1 = edges[e * 3 + 1];
    const float e2 = edges[e * 3 + 2];
    const int s = senders[e];
    const int r = receivers[e];
    float* esr = ws + ESR_OFF;
    atomicAdd(&esr[s * 8 + 0], e0);
    atomicAdd(&esr[s * 8 + 1], e1);
    atomicAdd(&esr[s * 8 + 2], e2);
    atomicAdd(&esr[s * 8 + 3], 1.0f);
    atomicAdd(&esr[r * 8 + 4], e0);
    atomicAdd(&esr[r * 8 + 5], e1);
    atomicAdd(&esr[r * 8 + 6], e2);
    atomicAdd(&esr[r * 8 + 7], 1.0f);
}

// Node MLP. Consts are read with wave-uniform addresses straight from global
// memory -> s_load/SGPR path (no per-lane LDS broadcast cost). 64-thread
// blocks give 782 blocks across 256 CUs.
__global__ __launch_bounds__(64) void node_kernel(
    const float* __restrict__ nodes,  // [N][16]
    const float* __restrict__ ws,
    const float* __restrict__ part_s,
    const float* __restrict__ part_r,
    float* __restrict__ out_nodes,    // d_out
    int nchunks)
{
    const int n = blockIdx.x * 64 + threadIdx.x;
    if (n >= N_NODES) return;

    const float4* np4 = (const float4*)(nodes + (size_t)n * 16);
    const float4 n0 = np4[0], n1 = np4[1], n2 = np4[2], n3 = np4[3];

    float4 es = make_float4(0.f, 0.f, 0.f, 0.f);
    float4 er = make_float4(0.f, 0.f, 0.f, 0.f);
    if (nchunks > 0) {
        for (int c = 0; c < nchunks; ++c) {
            const float4 a = *(const float4*)(part_s + (size_t)c * (N_NODES * 4) + (size_t)n * 4);
            const float4 b = *(const float4*)(part_r + (size_t)c * (N_NODES * 4) + (size_t)n * 4);
            es.x += a.x; es.y += a.y; es.z += a.z; es.w += a.w;
            er.x += b.x; er.y += b.y; er.z += b.z; er.w += b.w;
        }
    } else {
        const float4* p = (const float4*)(ws + ESR_OFF + (size_t)n * 8);
        es = p[0];
        er = p[1];
    }

    const float* cst = ws + CONSTS_OFF;  // wave-uniform reads below
    float acc = 0.f;
#pragma unroll 4
    for (int k = 0; k < 128; ++k) {
        const float4 m0 = *(const float4*)(cst + k * 32 + 0);
        const float4 m1 = *(const float4*)(cst + k * 32 + 4);
        const float4 m2 = *(const float4*)(cst + k * 32 + 8);
        const float4 m3 = *(const float4*)(cst + k * 32 + 12);
        const float4 q0 = *(const float4*)(cst + k * 32 + 16);
        const float4 q1 = *(const float4*)(cst + k * 32 + 20);
        const float4 q2 = *(const float4*)(cst + k * 32 + 24);
        float pre = q1.z
            + n0.x * m0.x + n0.y * m0.y + n0.z * m0.z + n0.w * m0.w
            + n1.x * m1.x + n1.y * m1.y + n1.z * m1.z + n1.w * m1.w
            + n2.x * m2.x + n2.y * m2.y + n2.z * m2.z + n2.w * m2.w
            + n3.x * m3.x + n3.y * m3.y + n3.z * m3.z + n3.w * m3.w
            + es.x * q0.x + es.y * q0.y + es.z * q0.z
            + er.x * q0.w + er.y * q1.x + er.z * q1.y
            + es.w * q1.w + er.w * q2.x;
        acc += fmaxf(pre, 0.f) * q2.y;
    }
    const float* scal = ws + SCAL_OFF;
    out_nodes[n] = acc + scal[0];
}

extern "C" void kernel_launch(void* const* d_in, const int* in_sizes, int n_in,
                              void* d_out, int out_size, void* d_ws, size_t ws_size,
                              hipStream_t stream) {
    const float* nodes     = (const float*)d_in[0];
    const float* edges     = (const float*)d_in[1];
    const float* globals_  = (const float*)d_in[2];
    const int*   senders   = (const int*)d_in[3];
    const int*   receivers = (const int*)d_in[4];
    const float* W_en = (const float*)d_in[5];
    const float* b_en = (const float*)d_in[6];
    const float* W_ee = (const float*)d_in[7];
    const float* b_ee = (const float*)d_in[8];
    const float* W1   = (const float*)d_in[9];
    const float* b1   = (const float*)d_in[10];
    const float* W2   = (const float*)d_in[11];
    const float* b2   = (const float*)d_in[12];
    const float* W_dn = (const float*)d_in[13];
    const float* b_dn = (const float*)d_in[14];
    const float* W_de = (const float*)d_in[15];
    const float* b_de = (const float*)d_in[16];

    float* ws = (float*)d_ws;
    float* out = (float*)d_out;

    precompute_kernel<<<27, 128, 0, stream>>>(
        globals_, W_en, b_en, W_ee, b_ee, W1, b1, W2, b2,
        W_dn, b_dn, W_de, b_de, ws);

    edge_out_kernel<<<(N_EDGES / 4 + 255) / 256, 256, 0, stream>>>(
        edges, ws, out + N_NODES);

    long ws_floats = (long)(ws_size / 4);
    long per_chunk = 2L * N_NODES * 4;  // part_s + part_r copies
    long avail = (ws_floats - PART_OFF) / per_chunk;
    int nchunks = (int)(avail < 0 ? 0 : (avail > MAX_CHUNKS ? MAX_CHUNKS : avail));

    float* part_s = ws + PART_OFF;
    float* part_r = part_s + (size_t)nchunks * (N_NODES * 4);

    if (nchunks >= 1) {
        int ce = (N_EDGES + nchunks - 1) / nchunks;
        ce = (ce + 7) & ~7;  // keep 8-edge groups int4-aligned
        dim3 grid(nchunks, 2 * NBINS);
        agg_kernel<<<grid, 512, 0, stream>>>(
            edges, senders, receivers, part_s, part_r, ce);
    } else {
        hipMemsetAsync(ws + ESR_OFF, 0, (size_t)N_NODES * 8 * sizeof(float), stream);
        edge_kernel_atomic<<<(N_EDGES + 255) / 256, 256, 0, stream>>>(
            edges, senders, receivers, ws);
    }

    node_kernel<<<(N_NODES + 63) / 64, 64, 0, stream>>>(
        nodes, ws, part_s, part_r, out, nchunks);
}